// Round 3
// baseline (153.576 us; speedup 1.0000x reference)
//
#include <hip/hip_runtime.h>

// Problem constants (hardcoded in reference)
constexpr int NB = 4096;  // batch
constexpr int NT = 128;   // TEXT_LEN
constexpr int NS = 128;   // retweet_user_size
constexpr int ND = 32;    // feature dim

// Key identity: softmax over a trailing axis of size 1 == 1.0 everywhere
// (exp(x-x)/sum == 1), and its inputs are finite (tanh-bounded * small
// weights). Hence As = ones(B,S,1), Ac = ones(B,T,1) and the output is
//   out[b, 0:32]  = sum_s X1[b,s,:]
//   out[b, 32:64] = sum_t C[b,t,:]
// Everything else (W, Ws, Wc, F, Hs, Hc, was, wac) is dead code w.r.t. the
// output. The kernel is a pure streaming column-sum: ~135 MB of HBM traffic.
//
// Structure: one 64-lane wave per batch element; no LDS, no barriers.
// Per batch, each tensor slice is 128 rows x 32 floats = 1024 float4s.
// Lane walks idx = lane, lane+64, ... (16 iters); since 64 % 8 == 0 the
// column-chunk (idx & 7) is loop-invariant, so the per-lane partial sum is
// a valid partial of output chunk (lane & 7). Wave reads are 64x16B = 1 KiB
// contiguous per instruction (perfectly coalesced). Cross-lane reduce via
// __shfl_down strides 32/16/8 combines lanes of equal (lane & 7).

__device__ __forceinline__ float4 f4_add(float4 a, float4 b) {
    return make_float4(a.x + b.x, a.y + b.y, a.z + b.z, a.w + b.w);
}

__device__ __forceinline__ float4 f4_shfl_down(float4 v, int off) {
    return make_float4(__shfl_down(v.x, off, 64), __shfl_down(v.y, off, 64),
                       __shfl_down(v.z, off, 64), __shfl_down(v.w, off, 64));
}

__global__ __launch_bounds__(256) void coatt_colsum(const float* __restrict__ C,
                                                    const float* __restrict__ X1,
                                                    float* __restrict__ out) {
    const int lane = threadIdx.x & 63;
    const int wave = threadIdx.x >> 6;                 // 4 waves per block
    const int b    = blockIdx.x * 4 + wave;            // one batch per wave

    const float4* x1 = reinterpret_cast<const float4*>(X1 + (size_t)b * NS * ND);
    const float4* cc = reinterpret_cast<const float4*>(C  + (size_t)b * NT * ND);

    float4 sx = make_float4(0.f, 0.f, 0.f, 0.f);
    float4 sc = make_float4(0.f, 0.f, 0.f, 0.f);
    // 16 iterations; unroll 8 keeps <=16 float4 loads in flight (64 VGPRs)
    // which hides latency without blowing the register budget.
    #pragma unroll 8
    for (int i = lane; i < (NS * ND) / 4; i += 64) {
        sx = f4_add(sx, x1[i]);
        sc = f4_add(sc, cc[i]);
    }

    // Reduce across the 8 row-groups (stride-8 lanes share a column chunk).
    #pragma unroll
    for (int off = 32; off >= 8; off >>= 1) {
        sx = f4_add(sx, f4_shfl_down(sx, off));
        sc = f4_add(sc, f4_shfl_down(sc, off));
    }

    if (lane < 8) {
        float4* o = reinterpret_cast<float4*>(out + (size_t)b * 64);
        o[lane]     = sx;   // sfinal: columns 0..31  (sum over S of X1)
        o[8 + lane] = sc;   // cfinal: columns 32..63 (sum over T of C)
    }
}

extern "C" void kernel_launch(void* const* d_in, const int* in_sizes, int n_in,
                              void* d_out, int out_size, void* d_ws, size_t ws_size,
                              hipStream_t stream) {
    // setup_inputs order: C, X1, W, Ws, Wc, was, wac
    const float* C  = (const float*)d_in[0];
    const float* X1 = (const float*)d_in[1];
    float* out = (float*)d_out;   // (B,1,64) fp32

    coatt_colsum<<<NB / 4, 256, 0, stream>>>(C, X1, out);
}

// Round 6
// 152.132 us; speedup vs baseline: 1.0095x; 1.0095x over previous
//
#include <hip/hip_runtime.h>

// Problem constants (hardcoded in reference)
constexpr int NB = 4096;  // batch
constexpr int NT = 128;   // TEXT_LEN
constexpr int NS = 128;   // retweet_user_size
constexpr int ND = 32;    // feature dim

// Math identity: softmax over a trailing axis of size 1 == 1.0, so
//   out[b, 0:32]  = sum_s X1[b,s,:]
//   out[b, 32:64] = sum_t C[b,t,:]
// Pure streaming column-sum. Round-3 data: FETCH 65.5MB (L3 absorbs half),
// dur 44us, Occupancy 30%, VALUBusy 1.5% -> latency-bound, not BW-bound.
//
// Fix: one wave per (batch, tensor) instead of per batch: 8192 waves /
// 2048 blocks -> 8 blocks/CU -> 32 waves/CU (occupancy cap). Per-lane:
// 16 float4 loads over a contiguous 16 KiB slice (fully coalesced,
// 1 KiB/wave-instr), 3 shfl_down rounds, lanes 0-7 store 8 float4.

__device__ __forceinline__ float4 f4_add(float4 a, float4 b) {
    return make_float4(a.x + b.x, a.y + b.y, a.z + b.z, a.w + b.w);
}

__device__ __forceinline__ float4 f4_shfl_down(float4 v, int off) {
    return make_float4(__shfl_down(v.x, off, 64), __shfl_down(v.y, off, 64),
                       __shfl_down(v.z, off, 64), __shfl_down(v.w, off, 64));
}

__global__ __launch_bounds__(256) void coatt_colsum(const float* __restrict__ C,
                                                    const float* __restrict__ X1,
                                                    float* __restrict__ out) {
    const int lane = threadIdx.x & 63;
    const int wv   = (blockIdx.x << 2) + (threadIdx.x >> 6);  // global wave id
    const int b    = wv >> 1;          // batch element
    const int isC  = wv & 1;           // 0 -> X1 (out cols 0..31), 1 -> C (32..63)

    const float* src = isC ? (C + (size_t)b * NT * ND)
                           : (X1 + (size_t)b * NS * ND);
    const float4* p = reinterpret_cast<const float4*>(src);

    float4 s = make_float4(0.f, 0.f, 0.f, 0.f);
    // 1024 float4s per slice, stride 64: 16 iterations. unroll 8 keeps
    // 8 loads in flight (~32 data VGPRs) without capping occupancy.
    #pragma unroll 8
    for (int i = lane; i < (NS * ND) / 4; i += 64) {
        s = f4_add(s, p[i]);
    }

    // Combine the 8 row-groups; stride-8 lanes share a column chunk
    // (64 % 8 == 0 keeps chunk = lane & 7 loop-invariant).
    #pragma unroll
    for (int off = 32; off >= 8; off >>= 1) {
        s = f4_add(s, f4_shfl_down(s, off));
    }

    if (lane < 8) {
        float4* o = reinterpret_cast<float4*>(out + (size_t)b * 64 + isC * 32);
        o[lane] = s;
    }
}

extern "C" void kernel_launch(void* const* d_in, const int* in_sizes, int n_in,
                              void* d_out, int out_size, void* d_ws, size_t ws_size,
                              hipStream_t stream) {
    // setup_inputs order: C, X1, W, Ws, Wc, was, wac
    const float* C  = (const float*)d_in[0];
    const float* X1 = (const float*)d_in[1];
    float* out = (float*)d_out;   // (B,1,64) fp32

    coatt_colsum<<<(NB * 2) / 4, 256, 0, stream>>>(C, X1, out);
}